// Round 2
// baseline (72.631 us; speedup 1.0000x reference)
//
#include <hip/hip_runtime.h>
#include <math.h>

#define H 8
#define B 64
#define D 512
#define EPS 1e-8f
#define INV_SQRT_D 0.04419417382415922f   // 1/sqrt(512)
#define LOG2E 1.4426950408889634f

__device__ __forceinline__ float fast_rcp(float x) { return __builtin_amdgcn_rcpf(x); }

// Kernel A: one block per (h,b). Stage q,k,v in LDS; each thread owns row i.
__global__ __launch_bounds__(512, 2) void attn_rows(
    const float* __restrict__ x,
    const float* __restrict__ Wq, const float* __restrict__ bq,
    const float* __restrict__ Wk, const float* __restrict__ bk,
    const float* __restrict__ Wv, const float* __restrict__ bv,
    float* __restrict__ ws)
{
    const int hb = blockIdx.x;          // 0..H*B-1
    const int h = hb >> 6;              // B == 64
    const int b = hb & 63;
    const int t = threadIdx.x;          // 0..511 == row i

    __shared__ float qs[D];
    __shared__ float kk[D];
    __shared__ float vs[D];

    const float xv = x[b * D + t];
    qs[t] = Wq[h * D + t] * xv + bq[h * D + t];
    kk[t] = Wk[h * D + t] * xv + bk[h * D + t];
    vs[t] = Wv[h * D + t] * xv + bv[h * D + t];
    __syncthreads();

    const float ki = kk[t];
    const float4* q4 = reinterpret_cast<const float4*>(qs);
    const float4* v4 = reinterpret_cast<const float4*>(vs);

    // Pass 1: row max of s_j = 1/(|q_j - k_i| + eps), 4 independent chains
    float m0 = -INFINITY, m1 = -INFINITY, m2 = -INFINITY, m3 = -INFINITY;
    for (int j = 0; j < D / 4; ++j) {
        float4 q = q4[j];
        m0 = fmaxf(m0, fast_rcp(fabsf(q.x - ki) + EPS));
        m1 = fmaxf(m1, fast_rcp(fabsf(q.y - ki) + EPS));
        m2 = fmaxf(m2, fast_rcp(fabsf(q.z - ki) + EPS));
        m3 = fmaxf(m3, fast_rcp(fabsf(q.w - ki) + EPS));
    }
    const float m = fmaxf(fmaxf(m0, m1), fmaxf(m2, m3));

    // Pass 2: sum of exp(s_j - m) and weighted sum with v_j
    float l0 = 0.f, l1 = 0.f, l2 = 0.f, l3 = 0.f;
    float a0 = 0.f, a1 = 0.f, a2 = 0.f, a3 = 0.f;
    for (int j = 0; j < D / 4; ++j) {
        float4 q = q4[j];
        float4 v = v4[j];
        float e0 = exp2f((fast_rcp(fabsf(q.x - ki) + EPS) - m) * LOG2E);
        float e1 = exp2f((fast_rcp(fabsf(q.y - ki) + EPS) - m) * LOG2E);
        float e2 = exp2f((fast_rcp(fabsf(q.z - ki) + EPS) - m) * LOG2E);
        float e3 = exp2f((fast_rcp(fabsf(q.w - ki) + EPS) - m) * LOG2E);
        l0 += e0; a0 = fmaf(e0, v.x, a0);
        l1 += e1; a1 = fmaf(e1, v.y, a1);
        l2 += e2; a2 = fmaf(e2, v.z, a2);
        l3 += e3; a3 = fmaf(e3, v.w, a3);
    }
    const float l = (l0 + l1) + (l2 + l3);
    const float a = (a0 + a1) + (a2 + a3);

    ws[hb * D + t] = a * fast_rcp(l) * INV_SQRT_D;
}

// Kernel B: out[b,i] = x[b,i] + sum_h ws[h,b,i]  (deterministic h-sum)
__global__ __launch_bounds__(256) void reduce_h(
    const float* __restrict__ x, const float* __restrict__ ws,
    float* __restrict__ out)
{
    const int i = blockIdx.x * 256 + threadIdx.x;   // 0..B*D-1
    float s = x[i];
    #pragma unroll
    for (int h = 0; h < H; ++h) s += ws[h * (B * D) + i];
    out[i] = s;
}

// Fallback (ws too small): fused, one block per b, loop h inside.
__global__ __launch_bounds__(512) void attn_fused(
    const float* __restrict__ x,
    const float* __restrict__ Wq, const float* __restrict__ bq,
    const float* __restrict__ Wk, const float* __restrict__ bk,
    const float* __restrict__ Wv, const float* __restrict__ bv,
    float* __restrict__ out)
{
    const int b = blockIdx.x;
    const int t = threadIdx.x;

    __shared__ float qs[D];
    __shared__ float kk[D];
    __shared__ float vs[D];

    const float xv = x[b * D + t];
    float total = 0.f;

    for (int h = 0; h < H; ++h) {
        __syncthreads();
        qs[t] = Wq[h * D + t] * xv + bq[h * D + t];
        kk[t] = Wk[h * D + t] * xv + bk[h * D + t];
        vs[t] = Wv[h * D + t] * xv + bv[h * D + t];
        __syncthreads();

        const float ki = kk[t];
        const float4* q4 = reinterpret_cast<const float4*>(qs);
        const float4* v4 = reinterpret_cast<const float4*>(vs);

        float m0 = -INFINITY, m1 = -INFINITY, m2 = -INFINITY, m3 = -INFINITY;
        for (int j = 0; j < D / 4; ++j) {
            float4 q = q4[j];
            m0 = fmaxf(m0, fast_rcp(fabsf(q.x - ki) + EPS));
            m1 = fmaxf(m1, fast_rcp(fabsf(q.y - ki) + EPS));
            m2 = fmaxf(m2, fast_rcp(fabsf(q.z - ki) + EPS));
            m3 = fmaxf(m3, fast_rcp(fabsf(q.w - ki) + EPS));
        }
        const float m = fmaxf(fmaxf(m0, m1), fmaxf(m2, m3));

        float l0 = 0.f, l1 = 0.f, l2 = 0.f, l3 = 0.f;
        float a0 = 0.f, a1 = 0.f, a2 = 0.f, a3 = 0.f;
        for (int j = 0; j < D / 4; ++j) {
            float4 q = q4[j];
            float4 v = v4[j];
            float e0 = exp2f((fast_rcp(fabsf(q.x - ki) + EPS) - m) * LOG2E);
            float e1 = exp2f((fast_rcp(fabsf(q.y - ki) + EPS) - m) * LOG2E);
            float e2 = exp2f((fast_rcp(fabsf(q.z - ki) + EPS) - m) * LOG2E);
            float e3 = exp2f((fast_rcp(fabsf(q.w - ki) + EPS) - m) * LOG2E);
            l0 += e0; a0 = fmaf(e0, v.x, a0);
            l1 += e1; a1 = fmaf(e1, v.y, a1);
            l2 += e2; a2 = fmaf(e2, v.z, a2);
            l3 += e3; a3 = fmaf(e3, v.w, a3);
        }
        const float l = (l0 + l1) + (l2 + l3);
        const float a = (a0 + a1) + (a2 + a3);
        total += a * fast_rcp(l) * INV_SQRT_D;
    }
    out[b * D + t] = xv + total;
}

extern "C" void kernel_launch(void* const* d_in, const int* in_sizes, int n_in,
                              void* d_out, int out_size, void* d_ws, size_t ws_size,
                              hipStream_t stream) {
    const float* x  = (const float*)d_in[0];
    const float* Wq = (const float*)d_in[1];
    const float* bq = (const float*)d_in[2];
    const float* Wk = (const float*)d_in[3];
    const float* bk = (const float*)d_in[4];
    const float* Wv = (const float*)d_in[5];
    const float* bv = (const float*)d_in[6];
    float* out = (float*)d_out;

    const size_t need = (size_t)H * B * D * sizeof(float);
    if (ws_size >= need) {
        float* ws = (float*)d_ws;
        attn_rows<<<H * B, 512, 0, stream>>>(x, Wq, bq, Wk, bk, Wv, bv, ws);
        reduce_h<<<(B * D) / 256, 256, 0, stream>>>(x, ws, out);
    } else {
        attn_fused<<<B, 512, 0, stream>>>(x, Wq, bq, Wk, bk, Wv, bv, out);
    }
}

// Round 3
// 42.690 us; speedup vs baseline: 1.7014x; 1.7014x over previous
//
#include <hip/hip_runtime.h>
#include <math.h>

#define H 8
#define B 64
#define D 512
#define EPS 1e-8f
#define INV_SQRT_D 0.04419417382415922f   // 1/sqrt(512)
#define LN2 0.6931471805599453f
#define EPS_LN2 6.931471805599453e-9f     // EPS * ln(2)

__device__ __forceinline__ float fast_rcp(float x) { return __builtin_amdgcn_rcpf(x); }
__device__ __forceinline__ float fast_exp2(float x) { return __builtin_amdgcn_exp2f(x); }

// Kernel A: one block per (h,b). Stage q,v in LDS; each thread owns row i.
// Softmax in log2-scaled space: T_j = log2e/(|q_j-k_i|+eps) = rcp(|d|*ln2 + eps*ln2)
// max_j T_j = rcp(dmin*ln2 + eps*ln2)  (rcp monotone decreasing on positives)
// weight_j = exp2(T_j - T_max); identical softmax result.
__global__ __launch_bounds__(512, 2) void attn_rows(
    const float* __restrict__ x,
    const float* __restrict__ Wq, const float* __restrict__ bq,
    const float* __restrict__ Wk, const float* __restrict__ bk,
    const float* __restrict__ Wv, const float* __restrict__ bv,
    float* __restrict__ ws)
{
    const int hb = blockIdx.x;          // 0..H*B-1
    const int h = hb >> 6;              // B == 64
    const int b = hb & 63;
    const int t = threadIdx.x;          // 0..511 == row i

    __shared__ float qs[D];
    __shared__ float vs[D];

    const float xv = x[b * D + t];
    qs[t] = Wq[h * D + t] * xv + bq[h * D + t];
    vs[t] = Wv[h * D + t] * xv + bv[h * D + t];
    const float ki = Wk[h * D + t] * xv + bk[h * D + t];
    __syncthreads();

    const float4* q4 = reinterpret_cast<const float4*>(qs);
    const float4* v4 = reinterpret_cast<const float4*>(vs);

    // Pass 1: dmin = min_j |q_j - k_i|   (2 VALU/elem, no transcendental)
    float d0 = INFINITY, d1 = INFINITY, d2 = INFINITY, d3 = INFINITY;
    for (int j = 0; j < D / 4; ++j) {
        float4 q = q4[j];
        d0 = fminf(d0, fabsf(q.x - ki));
        d1 = fminf(d1, fabsf(q.y - ki));
        d2 = fminf(d2, fabsf(q.z - ki));
        d3 = fminf(d3, fabsf(q.w - ki));
    }
    const float dmin = fminf(fminf(d0, d1), fminf(d2, d3));
    const float tmax = fast_rcp(fmaf(dmin, LN2, EPS_LN2));

    // Pass 2: T_j = rcp(|d|*ln2 + eps*ln2); e = exp2(T_j - tmax)
    float l0 = 0.f, l1 = 0.f, l2 = 0.f, l3 = 0.f;
    float a0 = 0.f, a1 = 0.f, a2 = 0.f, a3 = 0.f;
    for (int j = 0; j < D / 4; ++j) {
        float4 q = q4[j];
        float4 v = v4[j];
        float e0 = fast_exp2(fast_rcp(fmaf(fabsf(q.x - ki), LN2, EPS_LN2)) - tmax);
        float e1 = fast_exp2(fast_rcp(fmaf(fabsf(q.y - ki), LN2, EPS_LN2)) - tmax);
        float e2 = fast_exp2(fast_rcp(fmaf(fabsf(q.z - ki), LN2, EPS_LN2)) - tmax);
        float e3 = fast_exp2(fast_rcp(fmaf(fabsf(q.w - ki), LN2, EPS_LN2)) - tmax);
        l0 += e0; a0 = fmaf(e0, v.x, a0);
        l1 += e1; a1 = fmaf(e1, v.y, a1);
        l2 += e2; a2 = fmaf(e2, v.z, a2);
        l3 += e3; a3 = fmaf(e3, v.w, a3);
    }
    const float l = (l0 + l1) + (l2 + l3);
    const float a = (a0 + a1) + (a2 + a3);

    ws[hb * D + t] = a * fast_rcp(l) * INV_SQRT_D;
}

// Kernel B: out[b,i] = x[b,i] + sum_h ws[h,b,i]  (deterministic h-sum)
__global__ __launch_bounds__(256) void reduce_h(
    const float* __restrict__ x, const float* __restrict__ ws,
    float* __restrict__ out)
{
    const int i = blockIdx.x * 256 + threadIdx.x;   // 0..B*D-1
    float s = x[i];
    #pragma unroll
    for (int h = 0; h < H; ++h) s += ws[h * (B * D) + i];
    out[i] = s;
}

// Fallback (ws too small): fused, one block per b, loop h inside.
__global__ __launch_bounds__(512) void attn_fused(
    const float* __restrict__ x,
    const float* __restrict__ Wq, const float* __restrict__ bq,
    const float* __restrict__ Wk, const float* __restrict__ bk,
    const float* __restrict__ Wv, const float* __restrict__ bv,
    float* __restrict__ out)
{
    const int b = blockIdx.x;
    const int t = threadIdx.x;

    __shared__ float qs[D];
    __shared__ float vs[D];

    const float xv = x[b * D + t];
    float total = 0.f;

    for (int h = 0; h < H; ++h) {
        __syncthreads();
        qs[t] = Wq[h * D + t] * xv + bq[h * D + t];
        vs[t] = Wv[h * D + t] * xv + bv[h * D + t];
        const float ki = Wk[h * D + t] * xv + bk[h * D + t];
        __syncthreads();

        const float4* q4 = reinterpret_cast<const float4*>(qs);
        const float4* v4 = reinterpret_cast<const float4*>(vs);

        float d0 = INFINITY, d1 = INFINITY, d2 = INFINITY, d3 = INFINITY;
        for (int j = 0; j < D / 4; ++j) {
            float4 q = q4[j];
            d0 = fminf(d0, fabsf(q.x - ki));
            d1 = fminf(d1, fabsf(q.y - ki));
            d2 = fminf(d2, fabsf(q.z - ki));
            d3 = fminf(d3, fabsf(q.w - ki));
        }
        const float dmin = fminf(fminf(d0, d1), fminf(d2, d3));
        const float tmax = fast_rcp(fmaf(dmin, LN2, EPS_LN2));

        float l0 = 0.f, l1 = 0.f, l2 = 0.f, l3 = 0.f;
        float a0 = 0.f, a1 = 0.f, a2 = 0.f, a3 = 0.f;
        for (int j = 0; j < D / 4; ++j) {
            float4 q = q4[j];
            float4 v = v4[j];
            float e0 = fast_exp2(fast_rcp(fmaf(fabsf(q.x - ki), LN2, EPS_LN2)) - tmax);
            float e1 = fast_exp2(fast_rcp(fmaf(fabsf(q.y - ki), LN2, EPS_LN2)) - tmax);
            float e2 = fast_exp2(fast_rcp(fmaf(fabsf(q.z - ki), LN2, EPS_LN2)) - tmax);
            float e3 = fast_exp2(fast_rcp(fmaf(fabsf(q.w - ki), LN2, EPS_LN2)) - tmax);
            l0 += e0; a0 = fmaf(e0, v.x, a0);
            l1 += e1; a1 = fmaf(e1, v.y, a1);
            l2 += e2; a2 = fmaf(e2, v.z, a2);
            l3 += e3; a3 = fmaf(e3, v.w, a3);
        }
        const float l = (l0 + l1) + (l2 + l3);
        const float a = (a0 + a1) + (a2 + a3);
        total += a * fast_rcp(l) * INV_SQRT_D;
    }
    out[b * D + t] = xv + total;
}

extern "C" void kernel_launch(void* const* d_in, const int* in_sizes, int n_in,
                              void* d_out, int out_size, void* d_ws, size_t ws_size,
                              hipStream_t stream) {
    const float* x  = (const float*)d_in[0];
    const float* Wq = (const float*)d_in[1];
    const float* bq = (const float*)d_in[2];
    const float* Wk = (const float*)d_in[3];
    const float* bk = (const float*)d_in[4];
    const float* Wv = (const float*)d_in[5];
    const float* bv = (const float*)d_in[6];
    float* out = (float*)d_out;

    const size_t need = (size_t)H * B * D * sizeof(float);
    if (ws_size >= need) {
        float* ws = (float*)d_ws;
        attn_rows<<<H * B, 512, 0, stream>>>(x, Wq, bq, Wk, bk, Wv, bv, ws);
        reduce_h<<<(B * D) / 256, 256, 0, stream>>>(x, ws, out);
    } else {
        attn_fused<<<B, 512, 0, stream>>>(x, Wq, bq, Wk, bk, Wv, bv, out);
    }
}

// Round 4
// 39.863 us; speedup vs baseline: 1.8220x; 1.0709x over previous
//
#include <hip/hip_runtime.h>
#include <math.h>

#define H 8
#define B 64
#define D 512
#define EPS 1e-8f
#define INV_SQRT_D 0.04419417382415922f   // 1/sqrt(512)
#define LN2 0.6931471805599453f
#define EPS_LN2 6.931471805599453e-9f     // EPS * ln(2)

__device__ __forceinline__ float fast_rcp(float x) { return __builtin_amdgcn_rcpf(x); }
__device__ __forceinline__ float fast_exp2(float x) { return __builtin_amdgcn_exp2f(x); }

// ---------------------------------------------------------------------------
// Split kernel: 2 blocks per (h,b); each block processes ALL 512 rows over
// HALF of the j range (flash-style partial softmax), writing per-row
// (tmax, l, a) partials to ws. Grid 1024 blocks -> 4 blocks/CU -> 32 waves/CU.
// ws layout: 3 planar arrays of [2][H*B][D] floats: tmax | l | a
// ---------------------------------------------------------------------------
#define PLANE (2 * H * B * D)

__global__ __launch_bounds__(512, 8) void attn_split(
    const float* __restrict__ x,
    const float* __restrict__ Wq, const float* __restrict__ bq,
    const float* __restrict__ Wk, const float* __restrict__ bk,
    const float* __restrict__ Wv, const float* __restrict__ bv,
    float* __restrict__ ws)
{
    const int bid  = blockIdx.x;        // 0..2*H*B-1
    const int hb   = bid >> 1;
    const int half = bid & 1;
    const int h = hb >> 6;              // B == 64
    const int b = hb & 63;
    const int t = threadIdx.x;          // row i, 0..511

    __shared__ float qs[D / 2];
    __shared__ float vs[D / 2];

    // Stage this half's q (threads 0..255) and v (threads 256..511)
    if (t < 256) {
        const int j = half * 256 + t;
        qs[t] = Wq[h * D + j] * x[b * D + j] + bq[h * D + j];
    } else {
        const int j = half * 256 + (t - 256);
        vs[t - 256] = Wv[h * D + j] * x[b * D + j] + bv[h * D + j];
    }
    const float ki = Wk[h * D + t] * x[b * D + t] + bk[h * D + t];
    __syncthreads();

    const float4* q4 = reinterpret_cast<const float4*>(qs);
    const float4* v4 = reinterpret_cast<const float4*>(vs);

    // Pass 1: dmin over this half
    float d0 = INFINITY, d1 = INFINITY, d2 = INFINITY, d3 = INFINITY;
    for (int j = 0; j < D / 8; ++j) {
        float4 q = q4[j];
        d0 = fminf(d0, fabsf(q.x - ki));
        d1 = fminf(d1, fabsf(q.y - ki));
        d2 = fminf(d2, fabsf(q.z - ki));
        d3 = fminf(d3, fabsf(q.w - ki));
    }
    const float dmin = fminf(fminf(d0, d1), fminf(d2, d3));
    const float tmax = fast_rcp(fmaf(dmin, LN2, EPS_LN2));

    // Pass 2: l, a relative to this half's tmax
    float l0 = 0.f, l1 = 0.f, l2 = 0.f, l3 = 0.f;
    float a0 = 0.f, a1 = 0.f, a2 = 0.f, a3 = 0.f;
    for (int j = 0; j < D / 8; ++j) {
        float4 q = q4[j];
        float4 v = v4[j];
        float e0 = fast_exp2(fast_rcp(fmaf(fabsf(q.x - ki), LN2, EPS_LN2)) - tmax);
        float e1 = fast_exp2(fast_rcp(fmaf(fabsf(q.y - ki), LN2, EPS_LN2)) - tmax);
        float e2 = fast_exp2(fast_rcp(fmaf(fabsf(q.z - ki), LN2, EPS_LN2)) - tmax);
        float e3 = fast_exp2(fast_rcp(fmaf(fabsf(q.w - ki), LN2, EPS_LN2)) - tmax);
        l0 += e0; a0 = fmaf(e0, v.x, a0);
        l1 += e1; a1 = fmaf(e1, v.y, a1);
        l2 += e2; a2 = fmaf(e2, v.z, a2);
        l3 += e3; a3 = fmaf(e3, v.w, a3);
    }
    const float l = (l0 + l1) + (l2 + l3);
    const float a = (a0 + a1) + (a2 + a3);

    const int idx = (half * (H * B) + hb) * D + t;
    ws[idx]             = tmax;
    ws[PLANE + idx]     = l;
    ws[2 * PLANE + idx] = a;
}

// Merge halves + h-sum + residual: out[b,i] = x[b,i] + sum_h merge(h,b,i)
__global__ __launch_bounds__(256) void merge_halves(
    const float* __restrict__ x, const float* __restrict__ ws,
    float* __restrict__ out)
{
    const int i = blockIdx.x * 256 + threadIdx.x;   // 0..B*D-1
    const int b = i >> 9;
    const int dpos = i & 511;
    float s = x[i];
    #pragma unroll
    for (int h = 0; h < H; ++h) {
        const int hb = h * B + b;
        const int i0 = hb * D + dpos;
        const int i1 = (H * B + hb) * D + dpos;
        const float t0 = ws[i0],             t1 = ws[i1];
        const float l0 = ws[PLANE + i0],     l1 = ws[PLANE + i1];
        const float a0 = ws[2 * PLANE + i0], a1 = ws[2 * PLANE + i1];
        const float m  = fmaxf(t0, t1);
        const float s0 = fast_exp2(t0 - m);
        const float s1 = fast_exp2(t1 - m);
        const float l  = fmaf(l0, s0, l1 * s1);
        const float a  = fmaf(a0, s0, a1 * s1);
        s += a * fast_rcp(l) * INV_SQRT_D;
    }
    out[i] = s;
}

// ---------------------------------------------------------------------------
// Fallback path A (1 MB ws): one block per (h,b), full j per thread.
// ---------------------------------------------------------------------------
__global__ __launch_bounds__(512, 2) void attn_rows(
    const float* __restrict__ x,
    const float* __restrict__ Wq, const float* __restrict__ bq,
    const float* __restrict__ Wk, const float* __restrict__ bk,
    const float* __restrict__ Wv, const float* __restrict__ bv,
    float* __restrict__ ws)
{
    const int hb = blockIdx.x;
    const int h = hb >> 6;
    const int b = hb & 63;
    const int t = threadIdx.x;

    __shared__ float qs[D];
    __shared__ float vs[D];

    const float xv = x[b * D + t];
    qs[t] = Wq[h * D + t] * xv + bq[h * D + t];
    vs[t] = Wv[h * D + t] * xv + bv[h * D + t];
    const float ki = Wk[h * D + t] * xv + bk[h * D + t];
    __syncthreads();

    const float4* q4 = reinterpret_cast<const float4*>(qs);
    const float4* v4 = reinterpret_cast<const float4*>(vs);

    float d0 = INFINITY, d1 = INFINITY, d2 = INFINITY, d3 = INFINITY;
    for (int j = 0; j < D / 4; ++j) {
        float4 q = q4[j];
        d0 = fminf(d0, fabsf(q.x - ki));
        d1 = fminf(d1, fabsf(q.y - ki));
        d2 = fminf(d2, fabsf(q.z - ki));
        d3 = fminf(d3, fabsf(q.w - ki));
    }
    const float dmin = fminf(fminf(d0, d1), fminf(d2, d3));
    const float tmax = fast_rcp(fmaf(dmin, LN2, EPS_LN2));

    float l0 = 0.f, l1 = 0.f, l2 = 0.f, l3 = 0.f;
    float a0 = 0.f, a1 = 0.f, a2 = 0.f, a3 = 0.f;
    for (int j = 0; j < D / 4; ++j) {
        float4 q = q4[j];
        float4 v = v4[j];
        float e0 = fast_exp2(fast_rcp(fmaf(fabsf(q.x - ki), LN2, EPS_LN2)) - tmax);
        float e1 = fast_exp2(fast_rcp(fmaf(fabsf(q.y - ki), LN2, EPS_LN2)) - tmax);
        float e2 = fast_exp2(fast_rcp(fmaf(fabsf(q.z - ki), LN2, EPS_LN2)) - tmax);
        float e3 = fast_exp2(fast_rcp(fmaf(fabsf(q.w - ki), LN2, EPS_LN2)) - tmax);
        l0 += e0; a0 = fmaf(e0, v.x, a0);
        l1 += e1; a1 = fmaf(e1, v.y, a1);
        l2 += e2; a2 = fmaf(e2, v.z, a2);
        l3 += e3; a3 = fmaf(e3, v.w, a3);
    }
    const float l = (l0 + l1) + (l2 + l3);
    const float a = (a0 + a1) + (a2 + a3);

    ws[hb * D + t] = a * fast_rcp(l) * INV_SQRT_D;
}

__global__ __launch_bounds__(256) void reduce_h(
    const float* __restrict__ x, const float* __restrict__ ws,
    float* __restrict__ out)
{
    const int i = blockIdx.x * 256 + threadIdx.x;
    float s = x[i];
    #pragma unroll
    for (int h = 0; h < H; ++h) s += ws[h * (B * D) + i];
    out[i] = s;
}

// ---------------------------------------------------------------------------
// Fallback path B (no ws): fully fused.
// ---------------------------------------------------------------------------
__global__ __launch_bounds__(512) void attn_fused(
    const float* __restrict__ x,
    const float* __restrict__ Wq, const float* __restrict__ bq,
    const float* __restrict__ Wk, const float* __restrict__ bk,
    const float* __restrict__ Wv, const float* __restrict__ bv,
    float* __restrict__ out)
{
    const int b = blockIdx.x;
    const int t = threadIdx.x;

    __shared__ float qs[D];
    __shared__ float vs[D];

    const float xv = x[b * D + t];
    float total = 0.f;

    for (int h = 0; h < H; ++h) {
        __syncthreads();
        qs[t] = Wq[h * D + t] * xv + bq[h * D + t];
        vs[t] = Wv[h * D + t] * xv + bv[h * D + t];
        const float ki = Wk[h * D + t] * xv + bk[h * D + t];
        __syncthreads();

        const float4* q4 = reinterpret_cast<const float4*>(qs);
        const float4* v4 = reinterpret_cast<const float4*>(vs);

        float d0 = INFINITY, d1 = INFINITY, d2 = INFINITY, d3 = INFINITY;
        for (int j = 0; j < D / 4; ++j) {
            float4 q = q4[j];
            d0 = fminf(d0, fabsf(q.x - ki));
            d1 = fminf(d1, fabsf(q.y - ki));
            d2 = fminf(d2, fabsf(q.z - ki));
            d3 = fminf(d3, fabsf(q.w - ki));
        }
        const float dmin = fminf(fminf(d0, d1), fminf(d2, d3));
        const float tmax = fast_rcp(fmaf(dmin, LN2, EPS_LN2));

        float l0 = 0.f, l1 = 0.f, l2 = 0.f, l3 = 0.f;
        float a0 = 0.f, a1 = 0.f, a2 = 0.f, a3 = 0.f;
        for (int j = 0; j < D / 4; ++j) {
            float4 q = q4[j];
            float4 v = v4[j];
            float e0 = fast_exp2(fast_rcp(fmaf(fabsf(q.x - ki), LN2, EPS_LN2)) - tmax);
            float e1 = fast_exp2(fast_rcp(fmaf(fabsf(q.y - ki), LN2, EPS_LN2)) - tmax);
            float e2 = fast_exp2(fast_rcp(fmaf(fabsf(q.z - ki), LN2, EPS_LN2)) - tmax);
            float e3 = fast_exp2(fast_rcp(fmaf(fabsf(q.w - ki), LN2, EPS_LN2)) - tmax);
            l0 += e0; a0 = fmaf(e0, v.x, a0);
            l1 += e1; a1 = fmaf(e1, v.y, a1);
            l2 += e2; a2 = fmaf(e2, v.z, a2);
            l3 += e3; a3 = fmaf(e3, v.w, a3);
        }
        const float l = (l0 + l1) + (l2 + l3);
        const float a = (a0 + a1) + (a2 + a3);
        total += a * fast_rcp(l) * INV_SQRT_D;
    }
    out[b * D + t] = xv + total;
}

extern "C" void kernel_launch(void* const* d_in, const int* in_sizes, int n_in,
                              void* d_out, int out_size, void* d_ws, size_t ws_size,
                              hipStream_t stream) {
    const float* x  = (const float*)d_in[0];
    const float* Wq = (const float*)d_in[1];
    const float* bq = (const float*)d_in[2];
    const float* Wk = (const float*)d_in[3];
    const float* bk = (const float*)d_in[4];
    const float* Wv = (const float*)d_in[5];
    const float* bv = (const float*)d_in[6];
    float* out = (float*)d_out;

    const size_t need_split = (size_t)3 * PLANE * sizeof(float);   // 6 MB
    const size_t need_rows  = (size_t)H * B * D * sizeof(float);   // 1 MB

    if (ws_size >= need_split) {
        float* ws = (float*)d_ws;
        attn_split<<<2 * H * B, 512, 0, stream>>>(x, Wq, bq, Wk, bk, Wv, bv, ws);
        merge_halves<<<(B * D) / 256, 256, 0, stream>>>(x, ws, out);
    } else if (ws_size >= need_rows) {
        float* ws = (float*)d_ws;
        attn_rows<<<H * B, 512, 0, stream>>>(x, Wq, bq, Wk, bk, Wv, bv, ws);
        reduce_h<<<(B * D) / 256, 256, 0, stream>>>(x, ws, out);
    } else {
        attn_fused<<<B, 512, 0, stream>>>(x, Wq, bq, Wk, bk, Wv, bv, out);
    }
}